// Round 1
// baseline (334.551 us; speedup 1.0000x reference)
//
#include <hip/hip_runtime.h>
#include <hip/hip_bf16.h>
#include <stdint.h>

typedef unsigned short u16;
typedef __attribute__((ext_vector_type(8))) __bf16 bf16x8;
typedef __attribute__((ext_vector_type(4))) float f32x4;
typedef __attribute__((ext_vector_type(4))) float float4v;
typedef __attribute__((ext_vector_type(4))) u16  u16x4;

#define DEV __device__ __forceinline__

#define NB   2
#define CUR  1024
#define PREV 1024
#define TOT  2048
#define DM   1024
#define NH   16
#define DH   64

DEV u16 f2b(float f) {
    uint32_t u = __builtin_bit_cast(uint32_t, f);
    uint32_t r = (u + 0x7fffu + ((u >> 16) & 1u)) >> 16;   // RNE
    return (u16)r;
}
DEV float b2f(u16 u) {
    return __builtin_bit_cast(float, (uint32_t)u << 16);
}

typedef const __attribute__((address_space(1))) void* gptr_t;
typedef __attribute__((address_space(3))) void*       lptr_t;
DEV void async16(const void* g, void* l) {
    __builtin_amdgcn_global_load_lds((gptr_t)g, (lptr_t)l, 16, 0, 0);
}

// ---------------------------------------------------------------------------
// Generic bf16 MFMA GEMM: C[M,N] = A[M,K] * B[N,K]^T, batched over blockIdx.z.
// EPI: 1=Q->Abuf pack(+u,+v,shift)  2=KV->Bbuf/Vtmp pack  3=scores->E+colsum
//      4=PV->Obf  5=final(+x+bfc)->Y
// ---------------------------------------------------------------------------
template<int BM, int BN, int BK, int WM, int WN, int EPI>
__global__ __launch_bounds__(256)
void gemm_bt(const u16* __restrict__ A, const u16* __restrict__ B,
             int M, int N, int K, long sA, long sB, int bzBase,
             void* __restrict__ C0, void* __restrict__ C1,
             const float* __restrict__ F0, const float* __restrict__ F1)
{
    constexpr int WAVES_N = BN / WN;
    constexpr int MI = WM / 16, NI = WN / 16;
    static_assert((BM / WM) * (BN / WN) == 4, "4 waves");
    static_assert((BM * BK) % 2048 == 0 && (BN * BK) % 2048 == 0, "staging");

    __shared__ u16 lA[BM * BK];
    __shared__ u16 lB[BN * BK];

    const int bz  = blockIdx.z;
    const u16* Ab = A + (long)bz * sA;
    const u16* Bb = B + (long)bz * sB;
    const int m0 = blockIdx.y * BM, n0 = blockIdx.x * BN;
    const int tid = threadIdx.x, wave = tid >> 6, lane = tid & 63;
    const int wm0 = (wave / WAVES_N) * WM, wn0 = (wave % WAVES_N) * WN;

    f32x4 acc[MI][NI];
#pragma unroll
    for (int mi = 0; mi < MI; ++mi)
#pragma unroll
        for (int ni = 0; ni < NI; ++ni)
            acc[mi][ni] = f32x4{0.f, 0.f, 0.f, 0.f};

    for (int kt = 0; kt < K; kt += BK) {
        __syncthreads();
#pragma unroll
        for (int is = 0; is < (BM * BK) / 2048; ++is) {
            int e = is * 2048 + tid * 8;
            int r = e / BK, k = e % BK;
            async16(Ab + (long)(m0 + r) * K + kt + k, &lA[is * 2048 + wave * 512]);
        }
#pragma unroll
        for (int is = 0; is < (BN * BK) / 2048; ++is) {
            int e = is * 2048 + tid * 8;
            int r = e / BK, k = e % BK;
            async16(Bb + (long)(n0 + r) * K + kt + k, &lB[is * 2048 + wave * 512]);
        }
        __syncthreads();
#pragma unroll
        for (int ks = 0; ks < BK; ks += 32) {
            bf16x8 af[MI], br[NI];
#pragma unroll
            for (int mi = 0; mi < MI; ++mi)
                af[mi] = *(const bf16x8*)(const void*)&lA[(wm0 + mi * 16 + (lane & 15)) * BK + ks + ((lane >> 4) * 8)];
#pragma unroll
            for (int ni = 0; ni < NI; ++ni)
                br[ni] = *(const bf16x8*)(const void*)&lB[(wn0 + ni * 16 + (lane & 15)) * BK + ks + ((lane >> 4) * 8)];
#pragma unroll
            for (int mi = 0; mi < MI; ++mi)
#pragma unroll
                for (int ni = 0; ni < NI; ++ni)
                    acc[mi][ni] = __builtin_amdgcn_mfma_f32_16x16x32_bf16(af[mi], br[ni], acc[mi][ni], 0, 0, 0);
        }
    }

    const int gbz = bzBase + bz;
#pragma unroll
    for (int ni = 0; ni < NI; ++ni) {
        const int n = n0 + wn0 + ni * 16 + (lane & 15);
        float csum = 0.f;
#pragma unroll
        for (int mi = 0; mi < MI; ++mi) {
#pragma unroll
            for (int r = 0; r < 4; ++r) {
                const int m = m0 + wm0 + mi * 16 + ((lane >> 4) << 2) + r;
                float c = acc[mi][ni][r];
                if constexpr (EPI == 1) {            // q -> Abuf: [0:64]=q+u, [64:128]=shift(q+v)
                    int b = m >> 10, i = m & 1023, h = n >> 6, d = n & 63;
                    u16* Abuf = (u16*)C0;
                    Abuf[(((long)(b * NH + h)) * CUR + i) * 128 + d] = f2b(c + F0[n]);
                    float qv = c + F1[n];
                    if (b == 0) {
                        if (i > 0)    Abuf[(((long)h) * CUR + (i - 1)) * 128 + 64 + d] = f2b(qv);
                        if (i == 1023) Abuf[(((long)h) * CUR + 1023) * 128 + 64 + d] = 0;
                    } else {
                        Abuf[(((long)(NH + h)) * CUR + i) * 128 + 64 + d] = f2b(qv);
                    }
                } else if constexpr (EPI == 2) {     // kv -> Bbuf(k) / Vtmp(v)
                    int b = m >> 11, j = m & 2047;
                    if (n < DM) {
                        int h = n >> 6, d = n & 63;
                        ((u16*)C0)[(((long)(b * NH + h)) * TOT + j) * 128 + d] = f2b(c);
                    } else {
                        int h = (n - DM) >> 6, d = n & 63;
                        ((u16*)C1)[(((long)(b * NH + h)) * TOT + j) * 64 + d] = f2b(c);
                    }
                } else if constexpr (EPI == 3) {     // scores -> E (bf16) + colsum
                    float e = (n > m + PREV) ? 0.f : __expf(c * 0.125f);
                    ((u16*)C0)[((long)bz * M + m) * (long)N + n] = f2b(e);
                    csum += e;
                } else if constexpr (EPI == 4) {     // PV -> Obf (b,i, h*64+d)
                    int b = gbz >> 4, h = gbz & 15;
                    ((u16*)C0)[((long)b * CUR + m) * DM + h * DH + n] = f2b(c);
                } else if constexpr (EPI == 5) {     // final: y = x + C + bfc
                    ((float*)C0)[(long)m * DM + n] = F0[(long)m * DM + n] + c + F1[n];
                }
            }
        }
        if constexpr (EPI == 3) {
            csum += __shfl_xor(csum, 16);
            csum += __shfl_xor(csum, 32);
            if ((lane >> 4) == 0)
                atomicAdd(((float*)C1) + (long)gbz * TOT + n, csum);
        }
    }
}

// ---------------------------------------------------------------------------
__global__ __launch_bounds__(256)
void cvt_bf16(const float* __restrict__ src, u16* __restrict__ dst, int n4)
{
    int i = blockIdx.x * 256 + threadIdx.x;
    if (i < n4) {
        float4v f = ((const float4v*)src)[i];
        u16x4 o = {f2b(f[0]), f2b(f[1]), f2b(f[2]), f2b(f[3])};
        ((u16x4*)dst)[i] = o;
    }
}

__global__ __launch_bounds__(256)
void pack_H(const float* __restrict__ mem, const float* __restrict__ x, u16* __restrict__ dst)
{
    int i = blockIdx.x * 256 + threadIdx.x;   // over 4M/4 vec4s
    int e = i << 2;
    int b = e >> 21, r = e & ((1 << 21) - 1);
    const float* src = (r < (1 << 20)) ? (mem + ((long)b << 20) + r)
                                       : (x + ((long)b << 20) + (r - (1 << 20)));
    float4v f = *(const float4v*)src;
    u16x4 o = {f2b(f[0]), f2b(f[1]), f2b(f[2]), f2b(f[3])};
    ((u16x4*)dst)[i] = o;
}

__global__ __launch_bounds__(256)
void pack_pos(const float* __restrict__ pos, u16* __restrict__ Bbuf)
{
    int i = blockIdx.x * 256 + threadIdx.x;   // (h,j,d/4): 16*2048*16
    int e = i << 2;
    int h = e >> 17, r = e & 131071, j = r >> 6, d = r & 63;
    float4v f = *(const float4v*)(pos + (long)j * DM + h * DH + d);
    u16x4 o = {f2b(f[0]), f2b(f[1]), f2b(f[2]), f2b(f[3])};
    long base = ((long)h * TOT + j) * 128 + 64 + d;
    *(u16x4*)(Bbuf + base) = o;
    *(u16x4*)(Bbuf + base + (long)NH * TOT * 128) = o;
}

__global__ __launch_bounds__(256)
void vprime_kernel(const u16* __restrict__ Vtmp, const float* __restrict__ colsum,
                   u16* __restrict__ Vp, int bzBase)
{
    __shared__ float t[64][65];
    int bz = bzBase + blockIdx.y;
    int j0 = blockIdx.x * 64;
    const u16* src = Vtmp + ((long)bz * TOT + j0) * 64;
    const float* cs = colsum + (long)bz * TOT + j0;
    for (int e = threadIdx.x; e < 4096; e += 256) {
        int jl = e >> 6, d = e & 63;
        t[jl][d] = b2f(src[e]) / cs[jl];
    }
    __syncthreads();
    u16* dst = Vp + (long)bz * DH * TOT + j0;
    for (int e = threadIdx.x; e < 4096; e += 256) {
        int d = e >> 6, jl = e & 63;
        dst[(long)d * TOT + jl] = f2b(t[jl][d]);
    }
}

__global__ __launch_bounds__(256)
void ln_kernel(const float* __restrict__ Y, const float* __restrict__ gamma,
               const float* __restrict__ beta, float* __restrict__ out)
{
    const int row = blockIdx.x;
    const float* y = Y + (long)row * DM;
    float v[4];
    float s = 0.f;
#pragma unroll
    for (int t = 0; t < 4; ++t) { v[t] = y[threadIdx.x + t * 256]; s += v[t]; }
#pragma unroll
    for (int off = 32; off > 0; off >>= 1) s += __shfl_down(s, off);
    __shared__ float r1[4], r2[4];
    int wv = threadIdx.x >> 6, ln = threadIdx.x & 63;
    if (ln == 0) r1[wv] = s;
    __syncthreads();
    float mu = (r1[0] + r1[1] + r1[2] + r1[3]) * (1.f / DM);
    float q = 0.f;
#pragma unroll
    for (int t = 0; t < 4; ++t) { float d = v[t] - mu; q += d * d; }
#pragma unroll
    for (int off = 32; off > 0; off >>= 1) q += __shfl_down(q, off);
    if (ln == 0) r2[wv] = q;
    __syncthreads();
    float var = (r2[0] + r2[1] + r2[2] + r2[3]) * (1.f / DM);
    float inv = rsqrtf(var + 1e-5f);
#pragma unroll
    for (int t = 0; t < 4; ++t) {
        int c = threadIdx.x + t * 256;
        out[(long)row * DM + c] = (v[t] - mu) * inv * gamma[c] + beta[c];
    }
}

// ---------------------------------------------------------------------------
extern "C" void kernel_launch(void* const* d_in, const int* in_sizes, int n_in,
                              void* d_out, int out_size, void* d_ws, size_t ws_size,
                              hipStream_t stream)
{
    const float* x     = (const float*)d_in[0];
    const float* pos   = (const float*)d_in[1];
    const float* u     = (const float*)d_in[2];
    const float* vbias = (const float*)d_in[3];
    const float* mem   = (const float*)d_in[4];
    /* d_in[5] = tgt_mask: recomputed analytically (j > i + PREV) */
    const float* Wq    = (const float*)d_in[6];
    const float* Wkv   = (const float*)d_in[7];
    const float* Wfc   = (const float*)d_in[8];
    const float* bfc   = (const float*)d_in[9];
    const float* gamma = (const float*)d_in[10];
    const float* beta  = (const float*)d_in[11];
    float* out = (float*)d_out;

    char* w = (char*)d_ws;
    auto alloc = [&](size_t bytes) {
        char* p = w;
        w += (bytes + 255) & ~(size_t)255;
        return p;
    };
    u16*   Xb     = (u16*)alloc(2048UL * 1024 * 2);
    u16*   Hb     = (u16*)alloc(4096UL * 1024 * 2);
    u16*   Wqb    = (u16*)alloc(1024UL * 1024 * 2);
    u16*   Wkvb   = (u16*)alloc(2048UL * 1024 * 2);
    u16*   Wfcb   = (u16*)alloc(1024UL * 1024 * 2);
    u16*   Abuf   = (u16*)alloc(32UL * 1024 * 128 * 2);   // (b,h,i,128): q+u | shift(q+v)
    u16*   Bbuf   = (u16*)alloc(32UL * 2048 * 128 * 2);   // (b,h,j,128): k | pos
    u16*   Vtmp   = (u16*)alloc(32UL * 2048 * 64 * 2);    // (b,h,j,d)
    u16*   Vp     = (u16*)alloc(32UL * 64 * 2048 * 2);    // (b,h,d,j) = v/colsum
    float* colsum = (float*)alloc(32UL * 2048 * 4);
    u16*   Obf    = (u16*)alloc(2048UL * 1024 * 2);
    float* Yf     = (float*)alloc(2048UL * 1024 * 4);
    u16*   Ebuf   = (u16*)alloc(8UL * 1024 * 2048 * 2);   // E chunk: 8 (b,h) pairs

    hipMemsetAsync(colsum, 0, 32UL * 2048 * 4, stream);

    cvt_bf16<<<2048, 256, 0, stream>>>(x,   Xb,   2048 * 1024 / 4);
    cvt_bf16<<<1024, 256, 0, stream>>>(Wq,  Wqb,  1024 * 1024 / 4);
    cvt_bf16<<<2048, 256, 0, stream>>>(Wkv, Wkvb, 2048 * 1024 / 4);
    cvt_bf16<<<1024, 256, 0, stream>>>(Wfc, Wfcb, 1024 * 1024 / 4);
    pack_H  <<<4096, 256, 0, stream>>>(mem, x, Hb);
    pack_pos<<<2048, 256, 0, stream>>>(pos, Bbuf);

    // Q projection + Abuf pack (q+u, shifted q+v)
    gemm_bt<128, 128, 64, 64, 64, 1><<<dim3(8, 16, 1), 256, 0, stream>>>(
        Xb, Wqb, 2048, 1024, 1024, 0, 0, 0, Abuf, nullptr, u, vbias);
    // KV projection + Bbuf(k)/Vtmp(v) pack
    gemm_bt<128, 128, 64, 64, 64, 2><<<dim3(16, 32, 1), 256, 0, stream>>>(
        Hb, Wkvb, 4096, 2048, 1024, 0, 0, 0, Bbuf, Vtmp, nullptr, nullptr);

    for (int c = 0; c < 4; ++c) {
        int base = c * 8;
        // scores: E = exp(mask(S)/8), colsum += column sums
        gemm_bt<128, 128, 64, 64, 64, 3><<<dim3(16, 8, 8), 256, 0, stream>>>(
            Abuf + (long)base * 1024 * 128, Bbuf + (long)base * 2048 * 128,
            1024, 2048, 128, 1024 * 128, 2048 * 128, base, Ebuf, colsum, nullptr, nullptr);
        // v' = v / colsum, transposed to (d, j)
        vprime_kernel<<<dim3(32, 8), 256, 0, stream>>>(Vtmp, colsum, Vp, base);
        // O = E @ v'
        gemm_bt<128, 64, 64, 64, 32, 4><<<dim3(1, 8, 8), 256, 0, stream>>>(
            Ebuf, Vp + (long)base * 64 * 2048, 1024, 64, 2048,
            1024 * 2048, 64 * 2048, base, Obf, nullptr, nullptr, nullptr);
    }

    // y = x + O @ Wfc^T + bfc
    gemm_bt<128, 128, 64, 64, 64, 5><<<dim3(8, 16, 1), 256, 0, stream>>>(
        Obf, Wfcb, 2048, 1024, 1024, 0, 0, 0, Yf, nullptr, x, bfc);
    // LayerNorm -> out
    ln_kernel<<<2048, 256, 0, stream>>>(Yf, gamma, beta, out);
}

// Round 2
// 204.860 us; speedup vs baseline: 1.6331x; 1.6331x over previous
//
#include <hip/hip_runtime.h>
#include <hip/hip_bf16.h>
#include <stdint.h>

typedef unsigned short u16;
typedef __attribute__((ext_vector_type(8))) __bf16 bf16x8;
typedef __attribute__((ext_vector_type(4))) float f32x4;
typedef __attribute__((ext_vector_type(4))) float float4v;
typedef __attribute__((ext_vector_type(4))) u16  u16x4;
typedef __attribute__((ext_vector_type(8))) u16  u16x8;

#define DEV __device__ __forceinline__

#define NB   2
#define CUR  1024
#define PREV 1024
#define TOT  2048
#define DM   1024
#define NH   16
#define DH   64

DEV u16 f2b(float f) {
    uint32_t u = __builtin_bit_cast(uint32_t, f);
    uint32_t r = (u + 0x7fffu + ((u >> 16) & 1u)) >> 16;   // RNE
    return (u16)r;
}
DEV float b2f(u16 u) {
    return __builtin_bit_cast(float, (uint32_t)u << 16);
}

typedef const __attribute__((address_space(1))) void* gptr_t;
typedef __attribute__((address_space(3))) void*       lptr_t;
DEV void async16(const void* g, void* l) {
    __builtin_amdgcn_global_load_lds((gptr_t)g, (lptr_t)l, 16, 0, 0);
}

// ---------------------------------------------------------------------------
// Generic bf16 MFMA GEMM: C[M,N] = A[M,K] * B[N,K]^T, batched over blockIdx.z.
// EPI: 1=Q->Abuf pack(+u,+v,shift)  2=KV->Bbuf/Vtmp pack  3=scores->E+colsum
//      4=PV->Obf (K-trimmed to causal edge)  5=final(+x+bfc)->Y
// ---------------------------------------------------------------------------
template<int BM, int BN, int BK, int WM, int WN, int EPI>
__global__ __launch_bounds__(256)
void gemm_bt(const u16* __restrict__ A, const u16* __restrict__ B,
             int M, int N, int K, long sA, long sB, int bzBase,
             void* __restrict__ C0, void* __restrict__ C1,
             const float* __restrict__ F0, const float* __restrict__ F1)
{
    constexpr int WAVES_N = BN / WN;
    constexpr int MI = WM / 16, NI = WN / 16;
    static_assert((BM / WM) * (BN / WN) == 4, "4 waves");
    static_assert((BM * BK) % 2048 == 0 && (BN * BK) % 2048 == 0, "staging");

    __shared__ u16 lA[BM * BK];
    __shared__ u16 lB[BN * BK];

    const int bz  = blockIdx.z;
    const int m0 = blockIdx.y * BM, n0 = blockIdx.x * BN;
    const int tid = threadIdx.x, wave = tid >> 6, lane = tid & 63;

    if constexpr (EPI == 3) {
        // fully-masked tile: E = 0, no compute, no colsum contribution
        if (n0 > m0 + BM - 1 + PREV) {
            u16* Cz = (u16*)C0 + (long)bz * M * (long)N;
            u16x8 z8 = {};
#pragma unroll
            for (int e = tid * 8; e < BM * BN; e += 2048) {
                int r = e / BN, cc = e % BN;
                *(u16x8*)(Cz + (long)(m0 + r) * N + n0 + cc) = z8;
            }
            return;
        }
    }

    const u16* Ab = A + (long)bz * sA;
    const u16* Bb = B + (long)bz * sB;
    const int wm0 = (wave / WAVES_N) * WM, wn0 = (wave % WAVES_N) * WN;

    f32x4 acc[MI][NI];
#pragma unroll
    for (int mi = 0; mi < MI; ++mi)
#pragma unroll
        for (int ni = 0; ni < NI; ++ni)
            acc[mi][ni] = f32x4{0.f, 0.f, 0.f, 0.f};

    int Kend = K;
    if constexpr (EPI == 4) {
        int t = m0 + BM + PREV;       // multiple of BK by construction
        Kend = t < K ? t : K;
    }

    for (int kt = 0; kt < Kend; kt += BK) {
        __syncthreads();
#pragma unroll
        for (int is = 0; is < (BM * BK) / 2048; ++is) {
            int e = is * 2048 + tid * 8;
            int r = e / BK, k = e % BK;
            async16(Ab + (long)(m0 + r) * K + kt + k, &lA[is * 2048 + wave * 512]);
        }
#pragma unroll
        for (int is = 0; is < (BN * BK) / 2048; ++is) {
            int e = is * 2048 + tid * 8;
            int r = e / BK, k = e % BK;
            async16(Bb + (long)(n0 + r) * K + kt + k, &lB[is * 2048 + wave * 512]);
        }
        __syncthreads();
#pragma unroll
        for (int ks = 0; ks < BK; ks += 32) {
            bf16x8 af[MI], br[NI];
#pragma unroll
            for (int mi = 0; mi < MI; ++mi)
                af[mi] = *(const bf16x8*)(const void*)&lA[(wm0 + mi * 16 + (lane & 15)) * BK + ks + ((lane >> 4) * 8)];
#pragma unroll
            for (int ni = 0; ni < NI; ++ni)
                br[ni] = *(const bf16x8*)(const void*)&lB[(wn0 + ni * 16 + (lane & 15)) * BK + ks + ((lane >> 4) * 8)];
#pragma unroll
            for (int mi = 0; mi < MI; ++mi)
#pragma unroll
                for (int ni = 0; ni < NI; ++ni)
                    acc[mi][ni] = __builtin_amdgcn_mfma_f32_16x16x32_bf16(af[mi], br[ni], acc[mi][ni], 0, 0, 0);
        }
    }

    const int gbz = bzBase + bz;
#pragma unroll
    for (int ni = 0; ni < NI; ++ni) {
        const int n = n0 + wn0 + ni * 16 + (lane & 15);
        float csum = 0.f;
#pragma unroll
        for (int mi = 0; mi < MI; ++mi) {
#pragma unroll
            for (int r = 0; r < 4; ++r) {
                const int m = m0 + wm0 + mi * 16 + ((lane >> 4) << 2) + r;
                float c = acc[mi][ni][r];
                if constexpr (EPI == 1) {            // q -> Abuf: [0:64]=q+u, [64:128]=shift(q+v)
                    int b = gbz, i = m, h = n >> 6, d = n & 63;
                    u16* Abuf = (u16*)C0;
                    Abuf[(((long)(b * NH + h)) * CUR + i) * 128 + d] = f2b(c + F0[n]);
                    float qv = c + F1[n];
                    if (b == 0) {
                        if (i > 0)     Abuf[(((long)h) * CUR + (i - 1)) * 128 + 64 + d] = f2b(qv);
                        if (i == 1023) Abuf[(((long)h) * CUR + 1023) * 128 + 64 + d] = 0;
                    } else {
                        Abuf[(((long)(NH + h)) * CUR + i) * 128 + 64 + d] = f2b(qv);
                    }
                } else if constexpr (EPI == 2) {     // kv -> Bbuf(k) / Vtmp(v)
                    int b = m >> 11, j = m & 2047;
                    if (n < DM) {
                        int h = n >> 6, d = n & 63;
                        ((u16*)C0)[(((long)(b * NH + h)) * TOT + j) * 128 + d] = f2b(c);
                    } else {
                        int h = (n - DM) >> 6, d = n & 63;
                        ((u16*)C1)[(((long)(b * NH + h)) * TOT + j) * 64 + d] = f2b(c);
                    }
                } else if constexpr (EPI == 3) {     // scores -> E (bf16) + colsum
                    float e = (n > m + PREV) ? 0.f : __expf(c * 0.125f);
                    ((u16*)C0)[((long)bz * M + m) * (long)N + n] = f2b(e);
                    csum += e;
                } else if constexpr (EPI == 4) {     // PV -> Obf (b,i, h*64+d)
                    int b = gbz >> 4, h = gbz & 15;
                    ((u16*)C0)[((long)b * CUR + m) * DM + h * DH + n] = f2b(c);
                } else if constexpr (EPI == 5) {     // final: y = x + C + bfc
                    ((float*)C0)[(long)m * DM + n] = F0[(long)m * DM + n] + c + F1[n];
                }
            }
        }
        if constexpr (EPI == 3) {
            csum += __shfl_xor(csum, 16);
            csum += __shfl_xor(csum, 32);
            if ((lane >> 4) == 0)
                atomicAdd(((float*)C1) + (long)gbz * TOT + n, csum);
        }
    }
}

// ---------------------------------------------------------------------------
__global__ __launch_bounds__(256)
void cvt_bf16(const float* __restrict__ src, u16* __restrict__ dst, int n4)
{
    int i = blockIdx.x * 256 + threadIdx.x;
    if (i < n4) {
        float4v f = ((const float4v*)src)[i];
        u16x4 o = {f2b(f[0]), f2b(f[1]), f2b(f[2]), f2b(f[3])};
        ((u16x4*)dst)[i] = o;
    }
}

__global__ __launch_bounds__(256)
void pack_H(const float* __restrict__ mem, const float* __restrict__ x, u16* __restrict__ dst)
{
    int i = blockIdx.x * 256 + threadIdx.x;   // over 4M/4 vec4s
    int e = i << 2;
    int b = e >> 21, r = e & ((1 << 21) - 1);
    const float* src = (r < (1 << 20)) ? (mem + ((long)b << 20) + r)
                                       : (x + ((long)b << 20) + (r - (1 << 20)));
    float4v f = *(const float4v*)src;
    u16x4 o = {f2b(f[0]), f2b(f[1]), f2b(f[2]), f2b(f[3])};
    ((u16x4*)dst)[i] = o;
}

__global__ __launch_bounds__(256)
void pack_pos(const float* __restrict__ pos, u16* __restrict__ Bbuf)
{
    int i = blockIdx.x * 256 + threadIdx.x;   // (h,j,d/4): 16*2048*16
    int e = i << 2;
    int h = e >> 17, r = e & 131071, j = r >> 6, d = r & 63;
    float4v f = *(const float4v*)(pos + (long)j * DM + h * DH + d);
    u16x4 o = {f2b(f[0]), f2b(f[1]), f2b(f[2]), f2b(f[3])};
    long base = ((long)h * TOT + j) * 128 + 64 + d;
    *(u16x4*)(Bbuf + base) = o;
    *(u16x4*)(Bbuf + base + (long)NH * TOT * 128) = o;
}

__global__ __launch_bounds__(256)
void vprime_kernel(const u16* __restrict__ Vtmp, const float* __restrict__ colsum,
                   u16* __restrict__ Vp, int bzBase)
{
    __shared__ float t[64][65];
    int bz = bzBase + blockIdx.y;
    int j0 = blockIdx.x * 64;
    const u16* src = Vtmp + ((long)bz * TOT + j0) * 64;
    const float* cs = colsum + (long)bz * TOT + j0;
    for (int e = threadIdx.x; e < 4096; e += 256) {
        int jl = e >> 6, d = e & 63;
        t[jl][d] = b2f(src[e]) / cs[jl];
    }
    __syncthreads();
    u16* dst = Vp + (long)bz * DH * TOT + j0;
    for (int e = threadIdx.x; e < 4096; e += 256) {
        int d = e >> 6, jl = e & 63;
        dst[(long)d * TOT + jl] = f2b(t[jl][d]);
    }
}

__global__ __launch_bounds__(256)
void ln_kernel(const float* __restrict__ Y, const float* __restrict__ gamma,
               const float* __restrict__ beta, float* __restrict__ out)
{
    const int row = blockIdx.x;
    const float* y = Y + (long)row * DM;
    float v[4];
    float s = 0.f;
#pragma unroll
    for (int t = 0; t < 4; ++t) { v[t] = y[threadIdx.x + t * 256]; s += v[t]; }
#pragma unroll
    for (int off = 32; off > 0; off >>= 1) s += __shfl_down(s, off);
    __shared__ float r1[4], r2[4];
    int wv = threadIdx.x >> 6, ln = threadIdx.x & 63;
    if (ln == 0) r1[wv] = s;
    __syncthreads();
    float mu = (r1[0] + r1[1] + r1[2] + r1[3]) * (1.f / DM);
    float q = 0.f;
#pragma unroll
    for (int t = 0; t < 4; ++t) { float d = v[t] - mu; q += d * d; }
#pragma unroll
    for (int off = 32; off > 0; off >>= 1) q += __shfl_down(q, off);
    if (ln == 0) r2[wv] = q;
    __syncthreads();
    float var = (r2[0] + r2[1] + r2[2] + r2[3]) * (1.f / DM);
    float inv = rsqrtf(var + 1e-5f);
#pragma unroll
    for (int t = 0; t < 4; ++t) {
        int c = threadIdx.x + t * 256;
        out[(long)row * DM + c] = (v[t] - mu) * inv * gamma[c] + beta[c];
    }
}

// ---------------------------------------------------------------------------
extern "C" void kernel_launch(void* const* d_in, const int* in_sizes, int n_in,
                              void* d_out, int out_size, void* d_ws, size_t ws_size,
                              hipStream_t stream)
{
    const float* x     = (const float*)d_in[0];
    const float* pos   = (const float*)d_in[1];
    const float* u     = (const float*)d_in[2];
    const float* vbias = (const float*)d_in[3];
    const float* mem   = (const float*)d_in[4];
    /* d_in[5] = tgt_mask: recomputed analytically (j > i + PREV) */
    const float* Wq    = (const float*)d_in[6];
    const float* Wkv   = (const float*)d_in[7];
    const float* Wfc   = (const float*)d_in[8];
    const float* bfc   = (const float*)d_in[9];
    const float* gamma = (const float*)d_in[10];
    const float* beta  = (const float*)d_in[11];
    float* out = (float*)d_out;

    char* w = (char*)d_ws;
    auto alloc = [&](size_t bytes) {
        char* p = w;
        w += (bytes + 255) & ~(size_t)255;
        return p;
    };
    u16*   Hb     = (u16*)alloc(4096UL * 1024 * 2);       // (b, [mem;x], DM) bf16
    u16*   Wqb    = (u16*)alloc(1024UL * 1024 * 2);
    u16*   Wkvb   = (u16*)alloc(2048UL * 1024 * 2);
    u16*   Wfcb   = (u16*)alloc(1024UL * 1024 * 2);
    u16*   Abuf   = (u16*)alloc(32UL * 1024 * 128 * 2);   // (b,h,i,128): q+u | shift(q+v)
    u16*   Bbuf   = (u16*)alloc(32UL * 2048 * 128 * 2);   // (b,h,j,128): k | pos
    u16*   Vtmp   = (u16*)alloc(32UL * 2048 * 64 * 2);    // (b,h,j,d)
    u16*   Vp     = (u16*)alloc(32UL * 64 * 2048 * 2);    // (b,h,d,j) = v/colsum
    float* colsum = (float*)alloc(32UL * 2048 * 4);
    u16*   Obf    = (u16*)alloc(2048UL * 1024 * 2);
    float* Yf     = (float*)alloc(2048UL * 1024 * 4);
    u16*   Ebuf   = (u16*)alloc(32UL * 1024 * 2048 * 2);  // full E: 128 MB

    hipMemsetAsync(colsum, 0, 32UL * 2048 * 4, stream);

    cvt_bf16<<<1024, 256, 0, stream>>>(Wq,  Wqb,  1024 * 1024 / 4);
    cvt_bf16<<<2048, 256, 0, stream>>>(Wkv, Wkvb, 2048 * 1024 / 4);
    cvt_bf16<<<1024, 256, 0, stream>>>(Wfc, Wfcb, 1024 * 1024 / 4);
    pack_H  <<<4096, 256, 0, stream>>>(mem, x, Hb);
    pack_pos<<<2048, 256, 0, stream>>>(pos, Bbuf);

    // Q projection (reads x-half of Hb, z-batched over b) + Abuf pack
    gemm_bt<128, 128, 64, 64, 64, 1><<<dim3(8, 8, 2), 256, 0, stream>>>(
        Hb + 1024UL * 1024, Wqb, 1024, 1024, 1024, 2048L * 1024, 0, 0,
        Abuf, nullptr, u, vbias);
    // KV projection + Bbuf(k)/Vtmp(v) pack
    gemm_bt<128, 128, 64, 64, 64, 2><<<dim3(16, 32, 1), 256, 0, stream>>>(
        Hb, Wkvb, 4096, 2048, 1024, 0, 0, 0, Bbuf, Vtmp, nullptr, nullptr);

    // scores: E = exp(mask(S)/8) (zeros for fully-masked tiles), colsum += col sums
    gemm_bt<128, 128, 64, 64, 64, 3><<<dim3(16, 8, 32), 256, 0, stream>>>(
        Abuf, Bbuf, 1024, 2048, 128, 1024L * 128, 2048L * 128, 0,
        Ebuf, colsum, nullptr, nullptr);
    // v' = v / colsum, transposed to (d, j)
    vprime_kernel<<<dim3(32, 32), 256, 0, stream>>>(Vtmp, colsum, Vp, 0);
    // O = E @ v'   (K trimmed to causal edge: Kend = m0 + 64 + 1024)
    gemm_bt<64, 64, 64, 32, 32, 4><<<dim3(1, 16, 32), 256, 0, stream>>>(
        Ebuf, Vp, 1024, 64, 2048, 1024L * 2048, 64L * 2048, 0,
        Obf, nullptr, nullptr, nullptr);

    // y = x + O @ Wfc^T + bfc
    gemm_bt<128, 128, 64, 64, 64, 5><<<dim3(8, 16, 1), 256, 0, stream>>>(
        Obf, Wfcb, 2048, 1024, 1024, 0, 0, 0, Yf, nullptr, x, bfc);
    // LayerNorm -> out
    ln_kernel<<<2048, 256, 0, stream>>>(Yf, gamma, beta, out);
}

// Round 3
// 185.153 us; speedup vs baseline: 1.8069x; 1.1064x over previous
//
#include <hip/hip_runtime.h>
#include <hip/hip_bf16.h>
#include <stdint.h>

typedef unsigned short u16;
typedef __attribute__((ext_vector_type(8))) __bf16 bf16x8;
typedef __attribute__((ext_vector_type(4))) float f32x4;
typedef __attribute__((ext_vector_type(4))) float float4v;
typedef __attribute__((ext_vector_type(4))) u16  u16x4;

#define DEV __device__ __forceinline__

#define NB   2
#define CUR  1024
#define PREV 1024
#define TOT  2048
#define DM   1024
#define NH   16
#define DH   64

DEV u16 f2b(float f) {
    uint32_t u = __builtin_bit_cast(uint32_t, f);
    uint32_t r = (u + 0x7fffu + ((u >> 16) & 1u)) >> 16;   // RNE
    return (u16)r;
}
DEV float b2f(u16 u) {
    return __builtin_bit_cast(float, (uint32_t)u << 16);
}

typedef const __attribute__((address_space(1))) void* gptr_t;
typedef __attribute__((address_space(3))) void*       lptr_t;
DEV void async16(const void* g, void* l) {
    __builtin_amdgcn_global_load_lds((gptr_t)g, (lptr_t)l, 16, 0, 0);
}

// ---------------------------------------------------------------------------
// bf16 MFMA GEMM, TRANSPOSED output convention: C^T = A[M,K] * B[N,K]^T where
// M = the contiguous output dim (4 consecutive rows/lane -> packed stores).
// LDS XOR-swizzled (16B chunk ^ (row&7)); source-side pre-swizzle on
// global_load_lds, matching XOR on ds_read (both-sides rule).
// EPI: 1=Q->Abuf(+u,+v,shift)  2=KV->Bbuf/Vtmp  3=scores->E+colsum
//      4=PV->Obf (K-trim)      5=final(+x+bfc)->Yf
// ---------------------------------------------------------------------------
template<int BM, int BN, int BK, int WM, int WN, int EPI>
__global__ __launch_bounds__(256)
void gemm_bt(const u16* __restrict__ A, const u16* __restrict__ B,
             int M, int N, int K, long sA, long sB, int bzBase,
             void* __restrict__ C0, void* __restrict__ C1,
             const float* __restrict__ F0, const float* __restrict__ F1)
{
    constexpr int WAVES_N = BN / WN;
    constexpr int MI = WM / 16, NI = WN / 16;
    static_assert((BM / WM) * (BN / WN) == 4, "4 waves");
    static_assert(BK == 64, "swizzle assumes 8 chunks/row");
    static_assert((BM * BK) % 2048 == 0 && (BN * BK) % 2048 == 0, "staging");

    __shared__ u16 lA[BM * BK];
    __shared__ u16 lB[BN * BK];

    const int bz = blockIdx.z;
    const int m0 = blockIdx.y * BM, n0 = blockIdx.x * BN;
    const int tid = threadIdx.x, wave = tid >> 6, lane = tid & 63;

    if constexpr (EPI == 3) {
        if (m0 > n0 + BN - 1 + PREV) return;   // fully masked: never read by PV
    }

    const u16* Ab = A + (long)bz * sA;
    const u16* Bb = B + (long)bz * sB;
    const int wm0 = (wave / WAVES_N) * WM, wn0 = (wave % WAVES_N) * WN;
    const int quad = lane >> 4;

    f32x4 acc[MI][NI];
#pragma unroll
    for (int mi = 0; mi < MI; ++mi)
#pragma unroll
        for (int ni = 0; ni < NI; ++ni)
            acc[mi][ni] = f32x4{0.f, 0.f, 0.f, 0.f};

    int Kend = K;
    if constexpr (EPI == 4) {
        int t = n0 + BN + PREV;               // multiple of BK
        Kend = t < K ? t : K;
    }

    // staging geometry: thread loads 16B; row = is*32 + tid>>3, chunk = tid&7,
    // source chunk pre-swizzled by row&7 (LDS dest stays linear for DMA).
    const int srow = tid >> 3;
    const int ksw  = (((tid & 7) ^ ((tid >> 3) & 7)) << 3);

    for (int kt = 0; kt < Kend; kt += BK) {
        __syncthreads();
#pragma unroll
        for (int is = 0; is < (BM * BK) / 2048; ++is) {
            int r = is * 32 + srow;
            async16(Ab + (long)(m0 + r) * K + kt + ksw, &lA[is * 2048 + wave * 512]);
        }
#pragma unroll
        for (int is = 0; is < (BN * BK) / 2048; ++is) {
            int r = is * 32 + srow;
            async16(Bb + (long)(n0 + r) * K + kt + ksw, &lB[is * 2048 + wave * 512]);
        }
        __syncthreads();
#pragma unroll
        for (int ks = 0; ks < BK; ks += 32) {
            bf16x8 af[MI], br[NI];
#pragma unroll
            for (int mi = 0; mi < MI; ++mi)
                af[mi] = *(const bf16x8*)(const void*)
                    &lA[(wm0 + mi * 16 + (lane & 15)) * BK +
                        ((((ks >> 3) + quad) ^ (lane & 7)) << 3)];
#pragma unroll
            for (int ni = 0; ni < NI; ++ni)
                br[ni] = *(const bf16x8*)(const void*)
                    &lB[(wn0 + ni * 16 + (lane & 15)) * BK +
                        ((((ks >> 3) + quad) ^ (lane & 7)) << 3)];
#pragma unroll
            for (int mi = 0; mi < MI; ++mi)
#pragma unroll
                for (int ni = 0; ni < NI; ++ni)
                    acc[mi][ni] = __builtin_amdgcn_mfma_f32_16x16x32_bf16(af[mi], br[ni], acc[mi][ni], 0, 0, 0);
        }
    }

    const int gbz = bzBase + bz;

    if constexpr (EPI == 1) {                 // m = h*64+d, n = token i, bz = b
        u16* Abuf = (u16*)C0;
        const int b = gbz;
#pragma unroll
        for (int mi = 0; mi < MI; ++mi) {
            const int m = m0 + wm0 + mi * 16 + quad * 4;
            const int h = m >> 6, d = m & 63;
            const float4v uu = *(const float4v*)(F0 + m);
            const float4v vv = *(const float4v*)(F1 + m);
#pragma unroll
            for (int ni = 0; ni < NI; ++ni) {
                const int i = n0 + wn0 + ni * 16 + (lane & 15);
                u16x4 pu, pv;
#pragma unroll
                for (int r = 0; r < 4; ++r) {
                    pu[r] = f2b(acc[mi][ni][r] + uu[r]);
                    pv[r] = f2b(acc[mi][ni][r] + vv[r]);
                }
                *(u16x4*)(Abuf + (((long)(b * NH + h)) * CUR + i) * 128 + d) = pu;
                if (b == 0) {
                    if (i > 0)
                        *(u16x4*)(Abuf + (((long)h) * CUR + (i - 1)) * 128 + 64 + d) = pv;
                    if (i == 1023) {
                        u16x4 z = {};
                        *(u16x4*)(Abuf + (((long)h) * CUR + 1023) * 128 + 64 + d) = z;
                    }
                } else {
                    *(u16x4*)(Abuf + (((long)(NH + h)) * CUR + i) * 128 + 64 + d) = pv;
                }
            }
        }
    } else if constexpr (EPI == 2) {          // m = out-ch (k|v), n = b*2048+j
#pragma unroll
        for (int mi = 0; mi < MI; ++mi) {
            const int m = m0 + wm0 + mi * 16 + quad * 4;
            const bool isV = m >= DM;
            const int h = (m >> 6) & 15, d = m & 63;
#pragma unroll
            for (int ni = 0; ni < NI; ++ni) {
                const int n = n0 + wn0 + ni * 16 + (lane & 15);
                const int b = n >> 11, j = n & 2047;
                u16x4 p;
#pragma unroll
                for (int r = 0; r < 4; ++r) p[r] = f2b(acc[mi][ni][r]);
                if (!isV)
                    *(u16x4*)((u16*)C0 + (((long)(b * NH + h)) * TOT + j) * 128 + d) = p;
                else
                    *(u16x4*)((u16*)C1 + (((long)(b * NH + h)) * TOT + j) * 64 + d) = p;
            }
        }
    } else if constexpr (EPI == 3) {          // m = j, n = i, bz = bh
        u16* Eb = (u16*)C0 + (long)gbz * ((long)CUR * TOT);
        float ps[MI][4];
#pragma unroll
        for (int mi = 0; mi < MI; ++mi)
#pragma unroll
            for (int r = 0; r < 4; ++r) ps[mi][r] = 0.f;
#pragma unroll
        for (int mi = 0; mi < MI; ++mi) {
            const int m = m0 + wm0 + mi * 16 + quad * 4;
#pragma unroll
            for (int ni = 0; ni < NI; ++ni) {
                const int n = n0 + wn0 + ni * 16 + (lane & 15);
                u16x4 p;
#pragma unroll
                for (int r = 0; r < 4; ++r) {
                    float e = (m + r > n + PREV) ? 0.f : __expf(acc[mi][ni][r] * 0.125f);
                    p[r] = f2b(e);
                    ps[mi][r] += e;
                }
                *(u16x4*)(Eb + (long)n * TOT + m) = p;
            }
        }
        float* CS = (float*)C1 + (long)gbz * TOT;
#pragma unroll
        for (int mi = 0; mi < MI; ++mi)
#pragma unroll
            for (int r = 0; r < 4; ++r) {
                float vv = ps[mi][r];
                vv += __shfl_xor(vv, 1);
                vv += __shfl_xor(vv, 2);
                vv += __shfl_xor(vv, 4);
                vv += __shfl_xor(vv, 8);
                if ((lane & 15) == 0)
                    atomicAdd(CS + m0 + wm0 + mi * 16 + quad * 4 + r, vv);
            }
    } else if constexpr (EPI == 4) {          // m = d, n = i, bz = bh
        const int b = gbz >> 4, h = gbz & 15;
        u16* Ob = (u16*)C0 + (long)b * CUR * DM + h * DH;
#pragma unroll
        for (int mi = 0; mi < MI; ++mi) {
            const int m = m0 + wm0 + mi * 16 + quad * 4;
#pragma unroll
            for (int ni = 0; ni < NI; ++ni) {
                const int n = n0 + wn0 + ni * 16 + (lane & 15);
                u16x4 p;
#pragma unroll
                for (int r = 0; r < 4; ++r) p[r] = f2b(acc[mi][ni][r]);
                *(u16x4*)(Ob + (long)n * DM + m) = p;
            }
        }
    } else if constexpr (EPI == 5) {          // m = out col, n = token
#pragma unroll
        for (int mi = 0; mi < MI; ++mi) {
            const int m = m0 + wm0 + mi * 16 + quad * 4;
            const float4v bb = *(const float4v*)(F1 + m);
#pragma unroll
            for (int ni = 0; ni < NI; ++ni) {
                const int n = n0 + wn0 + ni * 16 + (lane & 15);
                const float4v xr = *(const float4v*)(F0 + (long)n * DM + m);
                float4v y;
#pragma unroll
                for (int r = 0; r < 4; ++r) y[r] = xr[r] + acc[mi][ni][r] + bb[r];
                *(float4v*)((float*)C0 + (long)n * DM + m) = y;
            }
        }
    }
}

// ---------------------------------------------------------------------------
__global__ __launch_bounds__(256)
void cvt_weights(const float* __restrict__ Wq, const float* __restrict__ Wkv,
                 const float* __restrict__ Wfc, u16* __restrict__ Wqb,
                 u16* __restrict__ Wkvb, u16* __restrict__ Wfcb)
{
    int i = blockIdx.x * 256 + threadIdx.x;   // 1M vec4s total
    const float* s; u16* d; int off;
    if (i < 262144)      { s = Wq;  d = Wqb;  off = i; }
    else if (i < 786432) { s = Wkv; d = Wkvb; off = i - 262144; }
    else                 { s = Wfc; d = Wfcb; off = i - 786432; }
    float4v f = ((const float4v*)s)[off];
    u16x4 o = {f2b(f[0]), f2b(f[1]), f2b(f[2]), f2b(f[3])};
    ((u16x4*)d)[off] = o;
}

__global__ __launch_bounds__(256)
void pack_H(const float* __restrict__ mem, const float* __restrict__ x, u16* __restrict__ dst)
{
    int i = blockIdx.x * 256 + threadIdx.x;
    int e = i << 2;
    int b = e >> 21, r = e & ((1 << 21) - 1);
    const float* src = (r < (1 << 20)) ? (mem + ((long)b << 20) + r)
                                       : (x + ((long)b << 20) + (r - (1 << 20)));
    float4v f = *(const float4v*)src;
    u16x4 o = {f2b(f[0]), f2b(f[1]), f2b(f[2]), f2b(f[3])};
    ((u16x4*)dst)[i] = o;
}

__global__ __launch_bounds__(256)
void pack_pos(const float* __restrict__ pos, u16* __restrict__ Bbuf)
{
    int i = blockIdx.x * 256 + threadIdx.x;   // (h,j,d/4): 16*2048*16
    int e = i << 2;
    int h = e >> 17, r = e & 131071, j = r >> 6, d = r & 63;
    float4v f = *(const float4v*)(pos + (long)j * DM + h * DH + d);
    u16x4 o = {f2b(f[0]), f2b(f[1]), f2b(f[2]), f2b(f[3])};
    long base = ((long)h * TOT + j) * 128 + 64 + d;
    *(u16x4*)(Bbuf + base) = o;
    *(u16x4*)(Bbuf + base + (long)NH * TOT * 128) = o;
}

__global__ __launch_bounds__(256)
void vprime_kernel(const u16* __restrict__ Vtmp, const float* __restrict__ colsum,
                   u16* __restrict__ Vp, int bzBase)
{
    __shared__ float t[64][65];
    int bz = bzBase + blockIdx.y;
    int j0 = blockIdx.x * 64;
    const u16* src = Vtmp + ((long)bz * TOT + j0) * 64;
    const float* cs = colsum + (long)bz * TOT + j0;
    for (int e = threadIdx.x; e < 4096; e += 256) {
        int jl = e >> 6, d = e & 63;
        t[jl][d] = b2f(src[e]) / cs[jl];
    }
    __syncthreads();
    u16* dst = Vp + (long)bz * DH * TOT + j0;
    for (int e = threadIdx.x; e < 4096; e += 256) {
        int d = e >> 6, jl = e & 63;
        dst[(long)d * TOT + jl] = f2b(t[jl][d]);
    }
}

__global__ __launch_bounds__(256)
void ln_kernel(const float* __restrict__ Y, const float* __restrict__ gamma,
               const float* __restrict__ beta, float* __restrict__ out)
{
    const int row = blockIdx.x;
    const float* y = Y + (long)row * DM;
    float v[4];
    float s = 0.f;
#pragma unroll
    for (int t = 0; t < 4; ++t) { v[t] = y[threadIdx.x + t * 256]; s += v[t]; }
#pragma unroll
    for (int off = 32; off > 0; off >>= 1) s += __shfl_down(s, off);
    __shared__ float r1[4], r2[4];
    int wv = threadIdx.x >> 6, ln = threadIdx.x & 63;
    if (ln == 0) r1[wv] = s;
    __syncthreads();
    float mu = (r1[0] + r1[1] + r1[2] + r1[3]) * (1.f / DM);
    float q = 0.f;
#pragma unroll
    for (int t = 0; t < 4; ++t) { float d = v[t] - mu; q += d * d; }
#pragma unroll
    for (int off = 32; off > 0; off >>= 1) q += __shfl_down(q, off);
    if (ln == 0) r2[wv] = q;
    __syncthreads();
    float var = (r2[0] + r2[1] + r2[2] + r2[3]) * (1.f / DM);
    float inv = rsqrtf(var + 1e-5f);
#pragma unroll
    for (int t = 0; t < 4; ++t) {
        int c = threadIdx.x + t * 256;
        out[(long)row * DM + c] = (v[t] - mu) * inv * gamma[c] + beta[c];
    }
}

// ---------------------------------------------------------------------------
extern "C" void kernel_launch(void* const* d_in, const int* in_sizes, int n_in,
                              void* d_out, int out_size, void* d_ws, size_t ws_size,
                              hipStream_t stream)
{
    const float* x     = (const float*)d_in[0];
    const float* pos   = (const float*)d_in[1];
    const float* u     = (const float*)d_in[2];
    const float* vbias = (const float*)d_in[3];
    const float* mem   = (const float*)d_in[4];
    /* d_in[5] = tgt_mask: recomputed analytically (j > i + PREV) */
    const float* Wq    = (const float*)d_in[6];
    const float* Wkv   = (const float*)d_in[7];
    const float* Wfc   = (const float*)d_in[8];
    const float* bfc   = (const float*)d_in[9];
    const float* gamma = (const float*)d_in[10];
    const float* beta  = (const float*)d_in[11];
    float* out = (float*)d_out;

    char* w = (char*)d_ws;
    auto alloc = [&](size_t bytes) {
        char* p = w;
        w += (bytes + 255) & ~(size_t)255;
        return p;
    };
    u16*   Hb     = (u16*)alloc(4096UL * 1024 * 2);       // (b, [mem;x], DM) bf16
    u16*   Wqb    = (u16*)alloc(1024UL * 1024 * 2);
    u16*   Wkvb   = (u16*)alloc(2048UL * 1024 * 2);
    u16*   Wfcb   = (u16*)alloc(1024UL * 1024 * 2);
    u16*   Abuf   = (u16*)alloc(32UL * 1024 * 128 * 2);   // (b,h,i,128): q+u | shift(q+v)
    u16*   Bbuf   = (u16*)alloc(32UL * 2048 * 128 * 2);   // (b,h,j,128): k | pos
    u16*   Vtmp   = (u16*)alloc(32UL * 2048 * 64 * 2);    // (b,h,j,d)
    u16*   Vp     = (u16*)alloc(32UL * 64 * 2048 * 2);    // (b,h,d,j) = v/colsum
    float* colsum = (float*)alloc(32UL * 2048 * 4);
    u16*   Obf    = (u16*)alloc(2048UL * 1024 * 2);
    float* Yf     = (float*)alloc(2048UL * 1024 * 4);
    u16*   Ebuf   = (u16*)alloc(32UL * 1024 * 2048 * 2);  // full E: (bh, i, j) 128 MB

    hipMemsetAsync(colsum, 0, 32UL * 2048 * 4, stream);

    cvt_weights<<<4096, 256, 0, stream>>>(Wq, Wkv, Wfc, Wqb, Wkvb, Wfcb);
    pack_H  <<<4096, 256, 0, stream>>>(mem, x, Hb);
    pack_pos<<<2048, 256, 0, stream>>>(pos, Bbuf);

    // Q^T: A=Wq (M=1024 out-ch), B=x tokens (N=1024, z=b) -> Abuf pack
    gemm_bt<128, 64, 64, 64, 32, 1><<<dim3(16, 8, 2), 256, 0, stream>>>(
        Wqb, Hb + 1024UL * 1024, 1024, 1024, 1024, 0, 2048L * 1024, 0,
        Abuf, nullptr, u, vbias);
    // KV^T: A=Wkv (M=2048), B=H (N=4096) -> Bbuf(k)/Vtmp(v)
    gemm_bt<128, 128, 64, 64, 64, 2><<<dim3(32, 16, 1), 256, 0, stream>>>(
        Wkvb, Hb, 2048, 4096, 1024, 0, 0, 0, Bbuf, Vtmp, nullptr, nullptr);

    // scores^T: A=Bbuf (M=2048 j), B=Abuf (N=1024 i), K=128, z=32 -> E + colsum
    gemm_bt<128, 128, 64, 64, 64, 3><<<dim3(8, 16, 32), 256, 0, stream>>>(
        Bbuf, Abuf, 2048, 1024, 128, 2048L * 128, 1024L * 128, 0,
        Ebuf, colsum, nullptr, nullptr);
    // v' = v / colsum, transposed to (d, j)
    vprime_kernel<<<dim3(32, 32), 256, 0, stream>>>(Vtmp, colsum, Vp, 0);
    // PV^T: A=Vp (M=64 d), B=E (N=1024 i), K=2048 trimmed, z=32 -> Obf
    gemm_bt<64, 64, 64, 32, 32, 4><<<dim3(16, 1, 32), 256, 0, stream>>>(
        Vp, Ebuf, 64, 1024, 2048, 64L * 2048, 1024L * 2048, 0,
        Obf, nullptr, nullptr, nullptr);

    // final^T: A=Wfc (M=1024 out-ch), B=Obf (N=2048 tokens) -> Yf = x + C + bfc
    gemm_bt<64, 128, 64, 32, 64, 5><<<dim3(16, 16, 1), 256, 0, stream>>>(
        Wfcb, Obf, 1024, 2048, 1024, 0, 0, 0, Yf, nullptr, x, bfc);
    // LayerNorm -> out
    ln_kernel<<<2048, 256, 0, stream>>>(Yf, gamma, beta, out);
}